// Round 5
// baseline (604.800 us; speedup 1.0000x reference)
//
#include <hip/hip_runtime.h>
#include <cmath>

// Problem constants
#define D_MODEL 1024
#define KOSC    256
#define NSEQ    4096
#define BATCH   4
#define NROW    (BATCH * NSEQ)   // 16384 rows (b*n)
#define JTOT    1792             // 6K proj + K phase

typedef short      s16x8 __attribute__((ext_vector_type(8)));
typedef float      f32x4 __attribute__((ext_vector_type(4)));

// async global->LDS, 16B per lane; LDS dest = wave-uniform base + lane*16
#define GL2LDS(gsrc, ldst)                                                      \
  __builtin_amdgcn_global_load_lds(                                             \
      (const __attribute__((address_space(1))) unsigned int*)(gsrc),            \
      (__attribute__((address_space(3))) unsigned int*)(ldst), 16, 0, 0)

__device__ __forceinline__ float sigm(float x) {
    return 1.0f / (1.0f + expf(-x));
}
__device__ __forceinline__ float softplusf_(float x) {
    return fmaxf(x, 0.0f) + log1pf(expf(-fabsf(x)));
}

// round-to-nearest-even bf16 split: f = hi + lo, residual ~2^-18 * |f|
__device__ __forceinline__ void bf16_split(float f, unsigned short& hi,
                                           unsigned short& lo) {
    unsigned u = __float_as_uint(f);
    unsigned r = u + 0x7FFFu + ((u >> 16) & 1u);
    hi = (unsigned short)(r >> 16);
    float fh = __uint_as_float((unsigned)hi << 16);
    float fl = f - fh;
    unsigned ul = __float_as_uint(fl);
    unsigned rl = ul + 0x7FFFu + ((ul >> 16) & 1u);
    lo = (unsigned short)(rl >> 16);
}

// ---------------------------------------------------------------------------
// prep: split_x (blocks 0..16383: 16384*1024 floats / (256 thr * 4)) +
//       split_w (blocks 16384..18175)
// ---------------------------------------------------------------------------
__global__ __launch_bounds__(256) void prep_kernel(
    const float* __restrict__ x,
    const float* __restrict__ Wproj, const float* __restrict__ Wphase,
    unsigned short* __restrict__ XH, unsigned short* __restrict__ XL,
    unsigned short* __restrict__ WH, unsigned short* __restrict__ WL)
{
    if (blockIdx.x < 16384) {
        int i = blockIdx.x * 256 + threadIdx.x;    // x4 floats
        float4 v = ((const float4*)x)[i];
        ushort4 h, l;
        bf16_split(v.x, h.x, l.x);
        bf16_split(v.y, h.y, l.y);
        bf16_split(v.z, h.z, l.z);
        bf16_split(v.w, h.w, l.w);
        ((ushort4*)XH)[i] = h;
        ((ushort4*)XL)[i] = l;
    } else {
        int i = (blockIdx.x - 16384) * 256 + threadIdx.x;   // x4 floats
        int elem = i << 2;
        int row = elem >> 10;
        int col = elem & 1023;
        const float* src = (row < 1536) ? (Wproj + (size_t)row * 1024 + col)
                                        : (Wphase + (size_t)(row - 1536) * 1024 + col);
        float4 v = *(const float4*)src;
        ushort4 h, l;
        bf16_split(v.x, h.x, l.x);
        bf16_split(v.y, h.y, l.y);
        bf16_split(v.z, h.z, l.z);
        bf16_split(v.w, h.w, l.w);
        ((ushort4*)WH)[i] = h;
        ((ushort4*)WL)[i] = l;
    }
}

// ---------------------------------------------------------------------------
// pack_wres: W_res fp32 (1024 x 1022) -> WPH bf16 (1024 x 1024) with the
// permuted column layout matching pack_rho:
//   j' < 767       : orig col j'
//   j' == 767      : 0 (pad)
//   768 <= j' <1023: orig col j'-1
//   j' == 1023     : 0 (pad)
// ---------------------------------------------------------------------------
__global__ __launch_bounds__(256) void pack_wres_kernel(
    const float* __restrict__ Wres, unsigned short* __restrict__ WPH)
{
    int idx = blockIdx.x * 256 + threadIdx.x;   // 0 .. 1024*1024-1
    int d = idx >> 10;
    int jp = idx & 1023;
    float v = 0.0f;
    if (jp < 767)                 v = Wres[(size_t)d * 1022 + jp];
    else if (jp >= 768 && jp < 1023) v = Wres[(size_t)d * 1022 + jp - 1];
    unsigned u = __float_as_uint(v);
    unsigned r = u + 0x7FFFu + ((u >> 16) & 1u);
    WPH[idx] = (unsigned short)(r >> 16);
}

// ---------------------------------------------------------------------------
// GEMM1 merged: PT[j, r] = sum_d Wcat[j,d] * x[r,d] + bcat[j]
//   jt = blockIdx.y (0..13). Tiles 2..5 (rows 256..767 = omega, phi) use the
//   3-term split-bf16 (angle is amplified by log-position <= 8.3, needs
//   ~fp32); all other tiles pass through sigmoids and are fine with 1 term.
// ---------------------------------------------------------------------------
__global__ __launch_bounds__(256, 3) void gemm1_kernel(
    const unsigned short* __restrict__ WH, const unsigned short* __restrict__ WL,
    const unsigned short* __restrict__ XH, const unsigned short* __restrict__ XL,
    const float* __restrict__ bproj, const float* __restrict__ bphase,
    float* __restrict__ PT)
{
    __shared__ __attribute__((aligned(16))) unsigned short AH[4096];
    __shared__ __attribute__((aligned(16))) unsigned short AL[4096];
    __shared__ __attribute__((aligned(16))) unsigned short BH[4096];
    __shared__ __attribute__((aligned(16))) unsigned short BL[4096];

    const int tid  = threadIdx.x;
    const int lane = tid & 63;
    const int w    = tid >> 6;          // wave 0..3
    const int wm   = w >> 1, wn = w & 1;
    const int jt   = blockIdx.y;
    const bool full = (jt >= 2 && jt <= 5);
    const int m0   = jt * 128;
    const int n0   = blockIdx.x * 128;
    const int fr   = lane & 15;
    const int fq   = lane >> 4;         // 0..3

    f32x4 acc[4][4];
    #pragma unroll
    for (int i = 0; i < 4; i++)
        #pragma unroll
        for (int j = 0; j < 4; j++) acc[i][j] = (f32x4){0.f, 0.f, 0.f, 0.f};

    for (int kc = 0; kc < 32; kc++) {
        const int kbase = kc * 32;
        __syncthreads();
        #pragma unroll
        for (int t = 0; t < 2; t++) {
            int G  = w * 128 + t * 64 + lane;       // granule index 0..511
            int gm = G & 127;
            int gq = G >> 7;
            size_t offA = (size_t)(m0 + gm) * 1024 + kbase + gq * 8;
            size_t offB = (size_t)(n0 + gm) * 1024 + kbase + gq * 8;
            int ldsg = (w * 128 + t * 64) * 8;      // wave-uniform base (shorts)
            GL2LDS(WH + offA, &AH[ldsg]);
            GL2LDS(XH + offB, &BH[ldsg]);
            if (full) {
                GL2LDS(WL + offA, &AL[ldsg]);
                GL2LDS(XL + offB, &BL[ldsg]);
            }
        }
        __syncthreads();

        s16x8 ah[4], al[4], bh[4], bl[4];
        #pragma unroll
        for (int f = 0; f < 4; f++) {
            int aoff = (fq * 128 + wm * 64 + f * 16 + fr) * 8;
            int boff = (fq * 128 + wn * 64 + f * 16 + fr) * 8;
            ah[f] = *(const s16x8*)&AH[aoff];
            bh[f] = *(const s16x8*)&BH[boff];
            if (full) {
                al[f] = *(const s16x8*)&AL[aoff];
                bl[f] = *(const s16x8*)&BL[boff];
            }
        }
        #pragma unroll
        for (int i = 0; i < 4; i++)
            #pragma unroll
            for (int j = 0; j < 4; j++) {
                acc[i][j] = __builtin_amdgcn_mfma_f32_16x16x32_bf16(ah[i], bh[j], acc[i][j], 0, 0, 0);
                if (full) {
                    acc[i][j] = __builtin_amdgcn_mfma_f32_16x16x32_bf16(ah[i], bl[j], acc[i][j], 0, 0, 0);
                    acc[i][j] = __builtin_amdgcn_mfma_f32_16x16x32_bf16(al[i], bh[j], acc[i][j], 0, 0, 0);
                }
            }
    }

    // epilogue: C/D layout col = lane&15 (n=r), row = (lane>>4)*4+reg (m=j)
    #pragma unroll
    for (int i = 0; i < 4; i++) {
        int mbase = m0 + wm * 64 + i * 16 + fq * 4;
        #pragma unroll
        for (int j = 0; j < 4; j++) {
            int n = n0 + wn * 64 + j * 16 + fr;
            #pragma unroll
            for (int rg = 0; rg < 4; rg++) {
                int m = mbase + rg;
                float bias = (m < 1536) ? bproj[m] : bphase[m - 1536];
                PT[(size_t)m * NROW + n] = acc[i][j][rg] + bias;
            }
        }
    }
}

// ---------------------------------------------------------------------------
// Scan kernel (register-resident): one block per (b,k) channel; each thread
// owns 16 consecutive n. float4 global I/O; alpha/drive/cos/sin live in
// registers; only the 256 thread-summaries go through LDS (3 KB).
// ---------------------------------------------------------------------------
__global__ __launch_bounds__(256) void scan_kernel(float* PT,
                                                   const float* lambda_ptr)
{
    const int bx = blockIdx.x;         // 0..1023
    const int k = bx & 255;
    const int b = bx >> 8;
    const int t = threadIdx.x;         // 0..255
    const size_t colb = (size_t)b * NSEQ;
    const size_t R = NROW;

    float* rowA  = PT + (size_t)(k)        * R + colb;  // a_raw -> rho_re
    float* rowW  = PT + (size_t)(256 + k)  * R + colb;  // w_raw -> rho_im
    float* rowP  = PT + (size_t)(512 + k)  * R + colb;  // p_raw -> g
    float* rowAl = PT + (size_t)(768 + k)  * R + colb;  // al_raw
    float* rowG  = PT + (size_t)(1024 + k) * R + colb;  // g_raw
    float* rowBe = PT + (size_t)(1280 + k) * R + colb;  // be_raw
    float* rowPq = PT + (size_t)(1536 + k) * R + colb;  // phase query

    __shared__ float s_sa[256], s_sbr[256], s_sbi[256];

    const float lam = *lambda_ptr;
    const int nb = t * 16;

    float alpha[16], dr[16], di[16], cs[16], sn[16];

    // phase 1: vectorized loads, activations, drive (all in registers)
    #pragma unroll
    for (int q = 0; q < 4; q++) {
        float4 a4 = *(const float4*)(rowA  + nb + q * 4);
        float4 w4 = *(const float4*)(rowW  + nb + q * 4);
        float4 p4 = *(const float4*)(rowP  + nb + q * 4);
        float4 l4 = *(const float4*)(rowAl + nb + q * 4);
        #pragma unroll
        for (int e = 0; e < 4; e++) {
            int i = q * 4 + e;
            float araw  = (&a4.x)[e];
            float wraw  = (&w4.x)[e];
            float praw  = (&p4.x)[e];
            float alraw = (&l4.x)[e];
            float A     = 3.0f * sigm(araw);
            alpha[i]    = sigm(alraw);
            float omega = softplusf_(wraw);
            float ang   = fmaf(omega, log1pf((float)(nb + i)), praw);
            sincosf(ang, &sn[i], &cs[i]);
            float amp = (1.0f - alpha[i]) * A;
            dr[i] = amp * cs[i];
            di[i] = amp * sn[i];
        }
    }

    // phase 2a: thread-local summary
    {
        float ap = 1.0f, br = 0.0f, bi = 0.0f;
        #pragma unroll
        for (int i = 0; i < 16; i++) {
            br = fmaf(alpha[i], br, dr[i]);
            bi = fmaf(alpha[i], bi, di[i]);
            ap *= alpha[i];
        }
        s_sa[t] = ap; s_sbr[t] = br; s_sbi[t] = bi;
    }
    __syncthreads();

    // phase 2b: Hillis-Steele inclusive scan over 256 summaries
    for (int off = 1; off < 256; off <<= 1) {
        float a2 = s_sa[t], b2r = s_sbr[t], b2i = s_sbi[t];
        float a1 = 1.0f, b1r = 0.0f, b1i = 0.0f;
        if (t >= off) { a1 = s_sa[t - off]; b1r = s_sbr[t - off]; b1i = s_sbi[t - off]; }
        __syncthreads();
        s_sa[t]  = a1 * a2;
        s_sbr[t] = fmaf(a2, b1r, b2r);
        s_sbi[t] = fmaf(a2, b1i, b2i);
        __syncthreads();
    }

    // phase 2c: carry + local replay; r overwrites dr/di
    {
        float cr = 0.0f, ci = 0.0f;
        if (t > 0) { cr = s_sbr[t - 1]; ci = s_sbi[t - 1]; }
        #pragma unroll
        for (int i = 0; i < 16; i++) {
            cr = fmaf(alpha[i], cr, dr[i]);
            ci = fmaf(alpha[i], ci, di[i]);
            dr[i] = cr;
            di[i] = ci;
        }
    }

    // phase 3: erase, normalize, demodulate, phase-gate; vectorized stores
    #pragma unroll
    for (int q = 0; q < 4; q++) {
        float4 be4 = *(const float4*)(rowBe + nb + q * 4);
        float4 g4  = *(const float4*)(rowG  + nb + q * 4);
        float4 pq4 = *(const float4*)(rowPq + nb + q * 4);
        float4 ore, oim, og;
        #pragma unroll
        for (int e = 0; e < 4; e++) {
            int i = q * 4 + e;
            float rr = dr[i], ri = di[i];
            float beta = sigm((&be4.x)[e]);
            float g    = sigm((&g4.x)[e]);
            float pq   = (&pq4.x)[e];

            float readout = rr * cs[i] + ri * sn[i];
            rr -= beta * readout * cs[i];
            ri -= beta * readout * sn[i];

            float modulus = sqrtf(rr * rr + ri * ri + 1e-8f);
            float scale = fmaxf(modulus, 1.0f);
            rr /= scale; ri /= scale;

            float rho_re = rr * cs[i] + ri * sn[i];
            float rho_im = -rr * sn[i] + ri * cs[i];

            float rho_norm = sqrtf(rho_re * rho_re + rho_im * rho_im + 1e-8f);
            float sq, cq;
            sincosf(pq, &sq, &cq);
            float pa = (rho_re * cq + rho_im * sq) / rho_norm;
            float gate = sigm(lam * pa);
            rho_re *= gate;
            rho_im *= gate;

            (&ore.x)[e] = rho_re;
            (&oim.x)[e] = rho_im;
            (&og.x)[e]  = g;
        }
        *(float4*)(rowA + nb + q * 4) = ore;
        *(float4*)(rowW + nb + q * 4) = oim;
        *(float4*)(rowP + nb + q * 4) = og;
    }
}

// ---------------------------------------------------------------------------
// pack_rho: chunked cross-products + transpose + bf16 split.
// Block = (r-chunk 32, k-chunk 64). LDS 3 x 65 x 33 floats (~26 KB).
// Output layout (permuted, matches pack_wres):
//   j' = k          : g*rho_re              (k = 0..255)
//   j' = 256+k      : g*rho_im
//   j' = 512+k      : gc*cross_re (k<255), pad0 at j'=767
//   j' = 768+k      : gc*cross_im (k<255), pad0 at j'=1023
// All stores are aligned s16x8.
// ---------------------------------------------------------------------------
__global__ __launch_bounds__(256) void pack_rho_kernel(
    const float* __restrict__ PT, unsigned short* __restrict__ RTH,
    unsigned short* __restrict__ RTL)
{
    __shared__ float s_re[65 * 33];
    __shared__ float s_im[65 * 33];
    __shared__ float s_g [65 * 33];

    const int tid = threadIdx.x;
    const int r0 = blockIdx.x * 32;
    const int k0 = blockIdx.y * 64;

    // load 65 k-rows x 32 r-cols, float4 global loads, scalar LDS writes
    for (int p = 0; p < 3; p++) {
        int fid = p * 256 + tid;
        if (fid < 520) {
            int kk = fid >> 3;             // 0..64
            int lr = (fid & 7) << 2;       // 0,4,..,28
            int a = kk * 33 + lr;
            if (k0 + kk <= 255) {
                size_t go = (size_t)(k0 + kk) * NROW + r0 + lr;
                float4 vre = *(const float4*)(PT + go);
                float4 vim = *(const float4*)(PT + (size_t)256 * NROW + go);
                float4 vg  = *(const float4*)(PT + (size_t)512 * NROW + go);
                s_re[a+0]=vre.x; s_re[a+1]=vre.y; s_re[a+2]=vre.z; s_re[a+3]=vre.w;
                s_im[a+0]=vim.x; s_im[a+1]=vim.y; s_im[a+2]=vim.z; s_im[a+3]=vim.w;
                s_g [a+0]=vg.x;  s_g [a+1]=vg.y;  s_g [a+2]=vg.z;  s_g [a+3]=vg.w;
            } else {
                s_re[a+0]=0.f; s_re[a+1]=0.f; s_re[a+2]=0.f; s_re[a+3]=0.f;
                s_im[a+0]=0.f; s_im[a+1]=0.f; s_im[a+2]=0.f; s_im[a+3]=0.f;
                s_g [a+0]=0.f; s_g [a+1]=0.f; s_g [a+2]=0.f; s_g [a+3]=0.f;
            }
        }
    }
    __syncthreads();

    const int r = tid >> 3;      // 0..31
    const int c = tid & 7;       // 0..7  -> kl = c*8..c*8+7

    float re0[8], im0[8], g0[8], re1[8], im1[8], g1[8];
    #pragma unroll
    for (int e = 0; e < 8; e++) {
        int a = (c * 8 + e) * 33 + r;
        re0[e] = s_re[a];      im0[e] = s_im[a];      g0[e] = s_g[a];
        re1[e] = s_re[a + 33]; im1[e] = s_im[a + 33]; g1[e] = s_g[a + 33];
    }

    const size_t rowoff = (size_t)(r0 + r) * 1024;
    const bool lastk = (blockIdx.y == 3);

    // seg0: g*re ; seg1: g*im ; seg2: cross_re ; seg3: cross_im
    #pragma unroll
    for (int seg = 0; seg < 4; seg++) {
        s16x8 hv, lv;
        #pragma unroll
        for (int e = 0; e < 8; e++) {
            float v;
            if (seg == 0)      v = g0[e] * re0[e];
            else if (seg == 1) v = g0[e] * im0[e];
            else {
                float gc = 0.5f * (g0[e] + g1[e]);
                if (seg == 2) v = gc * (re0[e] * re1[e] - im0[e] * im1[e]);
                else          v = gc * (re0[e] * im1[e] + im0[e] * re1[e]);
                if (lastk && c == 7 && e == 7) v = 0.0f;   // pad cols 767 / 1023
            }
            unsigned short h, l;
            bf16_split(v, h, l);
            hv[e] = (short)h; lv[e] = (short)l;
        }
        size_t off = rowoff + (size_t)seg * 256 + k0 + c * 8;
        *(s16x8*)&RTH[off] = hv;
        *(s16x8*)&RTL[off] = lv;
    }
}

// ---------------------------------------------------------------------------
// GEMM2 (2-term: W_res bf16, rho hi+lo): out[r,d] = rs * sum_j RT[r,j]*WP[d,j]
// ---------------------------------------------------------------------------
__global__ __launch_bounds__(256, 3) void gemm2_kernel(
    const unsigned short* __restrict__ WPH,
    const unsigned short* __restrict__ RTH, const unsigned short* __restrict__ RTL,
    const float* __restrict__ rs_ptr, float* __restrict__ out)
{
    __shared__ __attribute__((aligned(16))) unsigned short AH[4096];
    __shared__ __attribute__((aligned(16))) unsigned short BH[4096];
    __shared__ __attribute__((aligned(16))) unsigned short BL[4096];

    const int tid  = threadIdx.x;
    const int lane = tid & 63;
    const int w    = tid >> 6;
    const int wm   = w >> 1, wn = w & 1;
    const int m0   = blockIdx.y * 128;  // d tile
    const int n0   = blockIdx.x * 128;  // r tile
    const int fr   = lane & 15;
    const int fq   = lane >> 4;
    const float rs = *rs_ptr;

    f32x4 acc[4][4];
    #pragma unroll
    for (int i = 0; i < 4; i++)
        #pragma unroll
        for (int j = 0; j < 4; j++) acc[i][j] = (f32x4){0.f, 0.f, 0.f, 0.f};

    for (int kc = 0; kc < 32; kc++) {
        const int kbase = kc * 32;
        __syncthreads();
        #pragma unroll
        for (int t = 0; t < 2; t++) {
            int G  = w * 128 + t * 64 + lane;
            int gm = G & 127;
            int gq = G >> 7;
            size_t offA = (size_t)(m0 + gm) * 1024 + kbase + gq * 8;
            size_t offB = (size_t)(n0 + gm) * 1024 + kbase + gq * 8;
            int ldsg = (w * 128 + t * 64) * 8;
            GL2LDS(WPH + offA, &AH[ldsg]);
            GL2LDS(RTH + offB, &BH[ldsg]);
            GL2LDS(RTL + offB, &BL[ldsg]);
        }
        __syncthreads();

        s16x8 ah[4], bh[4], bl[4];
        #pragma unroll
        for (int f = 0; f < 4; f++) {
            int aoff = (fq * 128 + wm * 64 + f * 16 + fr) * 8;
            int boff = (fq * 128 + wn * 64 + f * 16 + fr) * 8;
            ah[f] = *(const s16x8*)&AH[aoff];
            bh[f] = *(const s16x8*)&BH[boff];
            bl[f] = *(const s16x8*)&BL[boff];
        }
        #pragma unroll
        for (int i = 0; i < 4; i++)
            #pragma unroll
            for (int j = 0; j < 4; j++) {
                acc[i][j] = __builtin_amdgcn_mfma_f32_16x16x32_bf16(ah[i], bh[j], acc[i][j], 0, 0, 0);
                acc[i][j] = __builtin_amdgcn_mfma_f32_16x16x32_bf16(ah[i], bl[j], acc[i][j], 0, 0, 0);
            }
    }

    #pragma unroll
    for (int i = 0; i < 4; i++) {
        int d = m0 + wm * 64 + i * 16 + fq * 4;
        #pragma unroll
        for (int j = 0; j < 4; j++) {
            int n = n0 + wn * 64 + j * 16 + fr;
            float4 v = { rs * acc[i][j][0], rs * acc[i][j][1],
                         rs * acc[i][j][2], rs * acc[i][j][3] };
            *(float4*)&out[(size_t)n * 1024 + d] = v;
        }
    }
}

// ---------------------------------------------------------------------------
extern "C" void kernel_launch(void* const* d_in, const int* in_sizes, int n_in,
                              void* d_out, int out_size, void* d_ws, size_t ws_size,
                              hipStream_t stream)
{
    const float* x      = (const float*)d_in[0];
    const float* Wproj  = (const float*)d_in[1];
    const float* bproj  = (const float*)d_in[2];
    const float* Wres   = (const float*)d_in[3];
    const float* Wphase = (const float*)d_in[4];
    const float* bphase = (const float*)d_in[5];
    const float* lam    = (const float*)d_in[6];
    const float* rs     = (const float*)d_in[7];
    float* out = (float*)d_out;

    // workspace layout (~124.8 MB):
    //   PT fp32 [1792][16384]           (117.4 MB)
    //   WH, WL bf16 [1792][1024]        (7.3 MB, after PT)
    // aliased into dead PT rows:
    //   RTH bf16 [16384][1024] = PT rows  768..1279  (after scan)
    //   RTL bf16 [16384][1024] = PT rows 1280..1791
    //   WPH bf16 [1024][1024]  = PT rows 0..31       (after pack_rho)
    // d_out doubles as XH/XL bf16 scratch until gemm2 overwrites it.
    float* PT = (float*)d_ws;
    unsigned short* WH  = (unsigned short*)((char*)d_ws + (size_t)JTOT * NROW * 4);
    unsigned short* WL  = WH + (size_t)JTOT * 1024;
    unsigned short* RTH = (unsigned short*)(PT + (size_t)768 * NROW);
    unsigned short* RTL = RTH + (size_t)NROW * 1024;
    unsigned short* WPH = (unsigned short*)PT;
    unsigned short* XH  = (unsigned short*)d_out;
    unsigned short* XL  = XH + (size_t)NROW * 1024;

    // x: 16384*1024 floats / (256*4 per block) = 16384 blocks; W: 1792 blocks
    hipLaunchKernelGGL(prep_kernel, dim3(16384 + 1792), dim3(256), 0, stream,
                       x, Wproj, Wphase, XH, XL, WH, WL);
    hipLaunchKernelGGL(gemm1_kernel, dim3(NROW / 128, 14), dim3(256), 0, stream,
                       WH, WL, XH, XL, bproj, bphase, PT);
    hipLaunchKernelGGL(scan_kernel, dim3(BATCH * KOSC), dim3(256), 0, stream,
                       PT, lam);
    hipLaunchKernelGGL(pack_rho_kernel, dim3(NROW / 32, 4), dim3(256), 0, stream,
                       PT, RTH, RTL);
    hipLaunchKernelGGL(pack_wres_kernel, dim3(1024 * 1024 / 256), dim3(256), 0, stream,
                       Wres, WPH);
    hipLaunchKernelGGL(gemm2_kernel, dim3(NROW / 128, 1024 / 128), dim3(256), 0, stream,
                       WPH, RTH, RTL, rs, out);
}